// Round 1
// 389.377 us; speedup vs baseline: 1.1046x; 1.1046x over previous
//
#include <hip/hip_runtime.h>
#include <hip/hip_fp16.h>

#define NUM_USERS 100000
#define NUM_ITEMS 50000
#define EMBED_DIM 64
#define N_NODES 150000
#define N_EDGES 4000000
#define N_LAYERS 3
#define BATCH 1024

#define NBKT 293            // buckets of 512 nodes: src >> 9
#define CHUNK 8192
#define NBLK_A ((N_EDGES + CHUNK - 1) / CHUNK)   // 489

typedef float f32x4 __attribute__((ext_vector_type(4)));   // native vec for nontemporal
typedef _Float16 f16x8 __attribute__((ext_vector_type(8)));
typedef float f32x4a __attribute__((ext_vector_type(4)));

// clear + mark batch users (replaces pathological rocclr fill: ~116us -> ~2us)
__global__ void clear_uflag_kernel(int* __restrict__ uflag) {
    int i = blockIdx.x * blockDim.x + threadIdx.x;
    if (i < NUM_USERS) uflag[i] = 0;
}

__global__ void mark_users_kernel(const int* __restrict__ users, int* __restrict__ uflag) {
    int i = blockIdx.x * blockDim.x + threadIdx.x;
    if (i < BATCH) uflag[users[i]] = 1;
}

// ---------------- init: fp16 table (all) + acc fp32 (needed rows only) -------
__global__ void init_emb_kernel(const float* __restrict__ ue, const float* __restrict__ ie,
                                const int* __restrict__ uflag,
                                float* __restrict__ acc, __half2* __restrict__ h0) {
    int i = blockIdx.x * blockDim.x + threadIdx.x;           // float4 index
    const int total  = N_NODES * (EMBED_DIM / 4);
    const int usplit = NUM_USERS * (EMBED_DIM / 4);
    if (i < total) {
        float4 v = (i < usplit) ? reinterpret_cast<const float4*>(ue)[i]
                                : reinterpret_cast<const float4*>(ie)[i - usplit];
        h0[i * 2 + 0] = __float22half2_rn(make_float2(v.x, v.y));
        h0[i * 2 + 1] = __float22half2_rn(make_float2(v.z, v.w));
        int n = i >> 4;
        if (n >= NUM_USERS || uflag[n])
            reinterpret_cast<float4*>(acc)[i] = v;
    }
}

// ---------------- CSR build: two-level LDS counting sort (NO global atomics) -
__global__ void histA_kernel(const int* __restrict__ src, int* __restrict__ hist) {
    __shared__ int lcnt[NBKT];
    int blk = blockIdx.x, t = threadIdx.x;
    for (int b = t; b < NBKT; b += 256) lcnt[b] = 0;
    __syncthreads();
    int e0 = blk * CHUNK;
    for (int i = t; i < CHUNK; i += 256) {
        int e = e0 + i;
        if (e < N_EDGES) atomicAdd(&lcnt[src[e] >> 9], 1);
    }
    __syncthreads();
    for (int b = t; b < NBKT; b += 256) hist[blk * NBKT + b] = lcnt[b];
}

// scanA: was a serial 489-iter loop on thread 0 (~latency chain). Now a
// 512-thread Hillis-Steele like scanB.
__global__ void scanA_kernel(const int* __restrict__ hist, int* __restrict__ off,
                             int* __restrict__ bucketTotal) {
    __shared__ int s[512];
    int b = blockIdx.x, t = threadIdx.x;         // 512 threads
    int v0 = (t < NBLK_A) ? hist[t * NBKT + b] : 0;
    s[t] = v0;
    __syncthreads();
    for (int o = 1; o < 512; o <<= 1) {
        int v = (t >= o) ? s[t - o] : 0;
        __syncthreads();
        s[t] += v;
        __syncthreads();
    }
    if (t < NBLK_A) off[t * NBKT + b] = s[t] - v0;   // exclusive
    if (t == NBLK_A - 1) bucketTotal[b] = s[t];
}

__global__ void scanB_kernel(const int* __restrict__ bucketTotal, int* __restrict__ bucketBase,
                             int* __restrict__ rowptr) {
    __shared__ int s[512];
    int t = threadIdx.x;                         // 512 threads
    s[t] = (t < NBKT) ? bucketTotal[t] : 0;
    __syncthreads();
    for (int o = 1; o < 512; o <<= 1) {
        int v = (t >= o) ? s[t - o] : 0;
        __syncthreads();
        s[t] += v;
        __syncthreads();
    }
    if (t < NBKT) bucketBase[t] = (t > 0) ? s[t - 1] : 0;
    if (t == 0) { bucketBase[NBKT] = s[NBKT - 1]; rowptr[N_NODES] = N_EDGES; }
}

// A3: partition edges to bucket segments (LDS ranks; coarse-coalesced writes).
__global__ void partA3_kernel(const int* __restrict__ src, const int* __restrict__ dst,
                              const float* __restrict__ val, const int* __restrict__ off,
                              const int* __restrict__ bucketBase, int2* __restrict__ tmp) {
    __shared__ int lcnt[NBKT];
    int blk = blockIdx.x, t = threadIdx.x;
    for (int b = t; b < NBKT; b += 256) lcnt[b] = 0;
    __syncthreads();
    int e0 = blk * CHUNK;
    for (int i = t; i < CHUNK; i += 256) {
        int e = e0 + i;
        if (e < N_EDGES) {
            int s = src[e];
            int b = s >> 9;
            int r = atomicAdd(&lcnt[b], 1);
            int pos = bucketBase[b] + off[blk * NBKT + b] + r;
            tmp[pos] = make_int2(dst[e] | ((s & 511) << 18), __float_as_int(val[e]));
        }
    }
}

// B: per bucket: node degrees -> LDS scan -> rowptr; scatter to final CSR.
__global__ void passB_kernel(const int2* __restrict__ tmp, const int* __restrict__ bucketBase,
                             int* __restrict__ rowptr, int2* __restrict__ edge_s) {
    __shared__ int sdeg[512];
    __shared__ int cursor[512];
    int bkt = blockIdx.x;
    int t = threadIdx.x;                         // 512 threads
    int base = bucketBase[bkt];
    int cntE = bucketBase[bkt + 1] - base;
    sdeg[t] = 0;
    __syncthreads();
    for (int i = t; i < cntE; i += 512)
        atomicAdd(&sdeg[tmp[base + i].x >> 18], 1);
    __syncthreads();
    int d = sdeg[t];
    for (int o = 1; o < 512; o <<= 1) {          // inclusive Hillis-Steele
        int v = (t >= o) ? sdeg[t - o] : 0;
        __syncthreads();
        sdeg[t] += v;
        __syncthreads();
    }
    int excl = sdeg[t] - d;
    cursor[t] = excl;
    int n = (bkt << 9) + t;
    if (n < N_NODES) rowptr[n] = base + excl;
    __syncthreads();
    for (int i = t; i < cntE; i += 512) {
        int2 e = tmp[base + i];
        int p = base + atomicAdd(&cursor[e.x >> 18], 1);
        edge_s[p] = make_int2(e.x & 0x3FFFF, e.y);
    }
}

// ---------------- one propagation layer (fp16 gather, fp32 accumulate) -------
template <bool WRITE_NXT>
__global__ void gather_layer_kernel(const __half* __restrict__ emb, const int* __restrict__ rowptr,
                                    const int2* __restrict__ eg, const int* __restrict__ uflag,
                                    __half* __restrict__ nxt, float* __restrict__ acc) {
    int tid = blockIdx.x * 256 + threadIdx.x;
    int n = tid >> 3;
    if (n >= N_NODES) return;
    bool needed = (n >= NUM_USERS) || uflag[n];
    if (!WRITE_NXT && !needed) return;            // last layer: output unread
    int c = (tid & 7) * 8;                        // dim offset (8 dims/thread)
    int beg = rowptr[n];
    int end = rowptr[n + 1];
    float a0 = 0.f, a1 = 0.f, a2 = 0.f, a3 = 0.f;
    float a4 = 0.f, a5 = 0.f, a6 = 0.f, a7 = 0.f;
    int j = beg;
    for (; j + 4 <= end; j += 4) {
        int2 e0 = eg[j];     int2 e1 = eg[j + 1];
        int2 e2 = eg[j + 2]; int2 e3 = eg[j + 3];
        uint4 r0 = *reinterpret_cast<const uint4*>(emb + (long)e0.x * EMBED_DIM + c);
        uint4 r1 = *reinterpret_cast<const uint4*>(emb + (long)e1.x * EMBED_DIM + c);
        uint4 r2 = *reinterpret_cast<const uint4*>(emb + (long)e2.x * EMBED_DIM + c);
        uint4 r3 = *reinterpret_cast<const uint4*>(emb + (long)e3.x * EMBED_DIM + c);
        float v0 = __int_as_float(e0.y), v1 = __int_as_float(e1.y);
        float v2 = __int_as_float(e2.y), v3 = __int_as_float(e3.y);
#define ACC8(R, V)                                                              \
        {                                                                       \
            const __half2* hp = reinterpret_cast<const __half2*>(&R);           \
            float2 f0 = __half22float2(hp[0]); float2 f1 = __half22float2(hp[1]);\
            float2 f2 = __half22float2(hp[2]); float2 f3 = __half22float2(hp[3]);\
            a0 += f0.x * V; a1 += f0.y * V; a2 += f1.x * V; a3 += f1.y * V;     \
            a4 += f2.x * V; a5 += f2.y * V; a6 += f3.x * V; a7 += f3.y * V;     \
        }
        ACC8(r0, v0) ACC8(r1, v1) ACC8(r2, v2) ACC8(r3, v3)
    }
    for (; j < end; ++j) {
        int2 e0 = eg[j];
        uint4 r0 = *reinterpret_cast<const uint4*>(emb + (long)e0.x * EMBED_DIM + c);
        float v0 = __int_as_float(e0.y);
        ACC8(r0, v0)
    }
#undef ACC8
    if (WRITE_NXT) {
        uint4 o;
        __half2* op = reinterpret_cast<__half2*>(&o);
        op[0] = __float22half2_rn(make_float2(a0, a1));
        op[1] = __float22half2_rn(make_float2(a2, a3));
        op[2] = __float22half2_rn(make_float2(a4, a5));
        op[3] = __float22half2_rn(make_float2(a6, a7));
        *reinterpret_cast<uint4*>(nxt + (long)n * EMBED_DIM + c) = o;
    }
    if (needed) {
        float* ap = acc + (long)n * EMBED_DIM + c;
        float4 x0 = *reinterpret_cast<float4*>(ap);
        float4 x1 = *reinterpret_cast<float4*>(ap + 4);
        x0.x += a0; x0.y += a1; x0.z += a2; x0.w += a3;
        x1.x += a4; x1.y += a5; x1.z += a6; x1.w += a7;
        *reinterpret_cast<float4*>(ap)     = x0;
        *reinterpret_cast<float4*>(ap + 4) = x1;
    }
}

// ---------------- pack fp32 acc -> fp16 A (batch users) and B (items) --------
// h1 is dead after the last gather layer (WRITE_NXT=false never writes nxt),
// so A16/B16 live there: A16 = h1 (1024x64), B16 = h1 + 1024*64 (50000x64).
__global__ void pack_ab_kernel(const float* __restrict__ acc, const int* __restrict__ users,
                               __half* __restrict__ A16, __half* __restrict__ B16) {
    int tid = blockIdx.x * 256 + threadIdx.x;
    const int total = (BATCH + NUM_ITEMS) * 8;       // 8 threads per row
    if (tid >= total) return;
    int r = tid >> 3;
    int c = (tid & 7) * 8;
    const float* src;
    __half* dstp;
    if (r < BATCH) {
        src  = acc + (long)users[r] * EMBED_DIM + c;
        dstp = A16 + (long)r * EMBED_DIM + c;
    } else {
        int i = r - BATCH;
        src  = acc + (long)(NUM_USERS + i) * EMBED_DIM + c;
        dstp = B16 + (long)i * EMBED_DIM + c;
    }
    float4 v0 = *reinterpret_cast<const float4*>(src);
    float4 v1 = *reinterpret_cast<const float4*>(src + 4);
    uint4 o;
    __half2* op = reinterpret_cast<__half2*>(&o);
    op[0] = __float22half2_rn(make_float2(v0.x, v0.y));
    op[1] = __float22half2_rn(make_float2(v0.z, v0.w));
    op[2] = __float22half2_rn(make_float2(v1.x, v1.y));
    op[3] = __float22half2_rn(make_float2(v1.z, v1.w));
    *reinterpret_cast<uint4*>(dstp) = o;
}

// ---------------- ratings: fp16 MFMA GEMM (fp32 accumulate) ------------------
// NT GEMM: out[u][i] = (1/16) * sum_k A16[u][k] * B16[i][k].
// mfma_f32_16x16x32_f16: A lane frag = 8 contiguous k at row (l&15), k-block
// (l>>4)*8; B identical from item rows (k-permutation cancels between A and B).
// C/D: col = l&15 (items), row = (l>>4)*4 + reg (users)  [HW-verified mapping].
__global__ __launch_bounds__(256)
void ratings_mfma_kernel(const __half* __restrict__ A16, const __half* __restrict__ B16,
                         float* __restrict__ out) {
    const int w  = threadIdx.x >> 6;            // wave 0..3
    const int l  = threadIdx.x & 63;
    const int u0 = blockIdx.y * 32 + (w & 1) * 16;
    const int i0 = blockIdx.x * 128 + (w >> 1) * 64;
    const int row = l & 15;
    const int kq  = (l >> 4) * 8;

    f32x4a acc0 = {0.f, 0.f, 0.f, 0.f};
    f32x4a acc1 = {0.f, 0.f, 0.f, 0.f};
    f32x4a acc2 = {0.f, 0.f, 0.f, 0.f};
    f32x4a acc3 = {0.f, 0.f, 0.f, 0.f};

#pragma unroll
    for (int ks = 0; ks < EMBED_DIM; ks += 32) {
        f16x8 a = *reinterpret_cast<const f16x8*>(A16 + (long)(u0 + row) * EMBED_DIM + ks + kq);
        int ir0 = i0 + 0 * 16 + row; if (ir0 >= NUM_ITEMS) ir0 = NUM_ITEMS - 1;
        int ir1 = i0 + 1 * 16 + row; if (ir1 >= NUM_ITEMS) ir1 = NUM_ITEMS - 1;
        int ir2 = i0 + 2 * 16 + row; if (ir2 >= NUM_ITEMS) ir2 = NUM_ITEMS - 1;
        int ir3 = i0 + 3 * 16 + row; if (ir3 >= NUM_ITEMS) ir3 = NUM_ITEMS - 1;
        f16x8 b0 = *reinterpret_cast<const f16x8*>(B16 + (long)ir0 * EMBED_DIM + ks + kq);
        f16x8 b1 = *reinterpret_cast<const f16x8*>(B16 + (long)ir1 * EMBED_DIM + ks + kq);
        f16x8 b2 = *reinterpret_cast<const f16x8*>(B16 + (long)ir2 * EMBED_DIM + ks + kq);
        f16x8 b3 = *reinterpret_cast<const f16x8*>(B16 + (long)ir3 * EMBED_DIM + ks + kq);
        acc0 = __builtin_amdgcn_mfma_f32_16x16x32_f16(a, b0, acc0, 0, 0, 0);
        acc1 = __builtin_amdgcn_mfma_f32_16x16x32_f16(a, b1, acc1, 0, 0, 0);
        acc2 = __builtin_amdgcn_mfma_f32_16x16x32_f16(a, b2, acc2, 0, 0, 0);
        acc3 = __builtin_amdgcn_mfma_f32_16x16x32_f16(a, b3, acc3, 0, 0, 0);
    }

    const float inv = 1.0f / 16.0f;              // (acc/4)·(acc/4) = acc·acc/16
    const int orow = u0 + (l >> 4) * 4;
    const int colb = l & 15;
#define STORE_FRAG(ACC, C)                                                      \
    {                                                                           \
        int col = i0 + (C) * 16 + colb;                                         \
        if (col < NUM_ITEMS) {                                                  \
            __builtin_nontemporal_store(ACC[0] * inv, out + (long)(orow + 0) * NUM_ITEMS + col); \
            __builtin_nontemporal_store(ACC[1] * inv, out + (long)(orow + 1) * NUM_ITEMS + col); \
            __builtin_nontemporal_store(ACC[2] * inv, out + (long)(orow + 2) * NUM_ITEMS + col); \
            __builtin_nontemporal_store(ACC[3] * inv, out + (long)(orow + 3) * NUM_ITEMS + col); \
        }                                                                       \
    }
    STORE_FRAG(acc0, 0)
    STORE_FRAG(acc1, 1)
    STORE_FRAG(acc2, 2)
    STORE_FRAG(acc3, 3)
#undef STORE_FRAG
}

extern "C" void kernel_launch(void* const* d_in, const int* in_sizes, int n_in,
                              void* d_out, int out_size, void* d_ws, size_t ws_size,
                              hipStream_t stream) {
    const float* ue    = (const float*)d_in[0];
    const float* ie    = (const float*)d_in[1];
    const float* val   = (const float*)d_in[2];
    const int*   src   = (const int*)d_in[3];
    const int*   dst   = (const int*)d_in[4];
    const int*   users = (const int*)d_in[5];
    float* out = (float*)d_out;

    // ws: acc fp32 (38.4 MB) + two fp16 tables (19.2 MB each) + uflag (400 KB)
    const size_t tab = (size_t)N_NODES * EMBED_DIM;
    float*  acc   = (float*)d_ws;
    __half* h0    = (__half*)(acc + tab);
    __half* h1    = h0 + tab;
    int*    uflag = (int*)(h1 + tab);

    // fp16 GEMM inputs live in h1 (dead after last gather layer)
    __half* A16 = h1;                                // 1024 x 64
    __half* B16 = h1 + (size_t)BATCH * EMBED_DIM;    // 50000 x 64

    // CSR scratch lives in d_out (ratings overwrites all of it at the end)
    char* ob = (char*)d_out;
    int2* edge_s      = (int2*)(ob);                     // [0,32MB)  final CSR (dst,val)
    int2* tmp         = (int2*)(ob + (64u << 20));       // [64,96MB) bucket-partitioned
    int*  hist        = (int*) (ob + (96u << 20));       // 489*293*4 = 573 KB
    int*  off         = (int*) (ob + (98u << 20));       // 573 KB
    int*  bucketTotal = (int*) (ob + (100u << 20));      // 1.2 KB
    int*  bucketBase  = (int*) (ob + (101u << 20));      // 1.2 KB
    int*  rowptr      = (int*) (ob + (102u << 20));      // 600 KB + 4

    // ---- needed-user flags (custom clear; rocclr fill kernel was ~116us) ----
    clear_uflag_kernel<<<(NUM_USERS + 255) / 256, 256, 0, stream>>>(uflag);
    mark_users_kernel<<<(BATCH + 255) / 256, 256, 0, stream>>>(users, uflag);

    const int totalv = N_NODES * EMBED_DIM / 4;
    init_emb_kernel<<<(totalv + 255) / 256, 256, 0, stream>>>(ue, ie, uflag, acc, (__half2*)h0);

    // ---- CSR build: LDS counting sort, no global atomics ----
    histA_kernel <<<NBLK_A, 256, 0, stream>>>(src, hist);
    scanA_kernel <<<NBKT, 512, 0, stream>>>(hist, off, bucketTotal);
    scanB_kernel <<<1, 512, 0, stream>>>(bucketTotal, bucketBase, rowptr);
    partA3_kernel<<<NBLK_A, 256, 0, stream>>>(src, dst, val, off, bucketBase, tmp);
    passB_kernel <<<NBKT, 512, 0, stream>>>(tmp, bucketBase, rowptr, edge_s);

    // ---- 3 propagation layers (fp16 gather form) ----
    const int ggrid = (N_NODES * 8 + 255) / 256;
    gather_layer_kernel<true><<<ggrid, 256, 0, stream>>>(h0, rowptr, edge_s, uflag, h1, acc);
    gather_layer_kernel<true><<<ggrid, 256, 0, stream>>>(h1, rowptr, edge_s, uflag, h0, acc);
    gather_layer_kernel<false><<<ggrid, 256, 0, stream>>>(h0, rowptr, edge_s, uflag, h1, acc);

    // ---- pack needed rows to fp16, then MFMA ratings GEMM ----
    const int packn = (BATCH + NUM_ITEMS) * 8;
    pack_ab_kernel<<<(packn + 255) / 256, 256, 0, stream>>>(acc, users, A16, B16);

    dim3 rgrid((NUM_ITEMS + 127) / 128, BATCH / 32);
    ratings_mfma_kernel<<<rgrid, 256, 0, stream>>>(A16, B16, out);
}